// Round 6
// baseline (462.191 us; speedup 1.0000x reference)
//
#include <hip/hip_runtime.h>
#include <hip/hip_bf16.h>
#include <math.h>

#define BB 2
#define NN 2048
#define DD 512
#define HH 8
#define LL 2
#define TT (BB*NN)   // 4096 tokens

typedef short short8 __attribute__((ext_vector_type(8)));
typedef float floatx4 __attribute__((ext_vector_type(4)));

__device__ __forceinline__ unsigned short f2b(float v) {
    union { float f; unsigned u; } x; x.f = v;
    unsigned r = x.u + 0x7fff + ((x.u >> 16) & 1);   // RNE
    return (unsigned short)(r >> 16);
}

#if __has_builtin(__builtin_amdgcn_global_load_lds)
#define HAVE_ASYNC 1
__device__ __forceinline__ void g2l16(const void* g, void* l) {
    __builtin_amdgcn_global_load_lds(
        (const __attribute__((address_space(1))) unsigned int*)g,
        (__attribute__((address_space(3))) unsigned int*)l, 16, 0, 0);
}
#else
#define HAVE_ASYNC 0
#endif

// ---------------- embed: h = inputs_embeds + pos_emb ----------------
__global__ __launch_bounds__(256) void k_embed(const float* __restrict__ emb,
                                               const float* __restrict__ pos,
                                               float* __restrict__ h) {
    int i = blockIdx.x * 256 + threadIdx.x;
    h[i] = emb[i] + pos[i & (NN * DD - 1)];
}

// ---------------- layernorm: x = LN(h)*g + b  (bf16 out), one block per token ----------------
__global__ __launch_bounds__(256) void k_ln(const float* __restrict__ hin,
                                            unsigned short* __restrict__ xout,
                                            const float* __restrict__ g,
                                            const float* __restrict__ b) {
    __shared__ float red[4];
    __shared__ float bc1, bc2;
    int t = blockIdx.x;
    int tid = threadIdx.x;
    int lane = tid & 63, wv = tid >> 6;
    const float* row = hin + (size_t)t * DD;
    float v0 = row[tid];
    float v1 = row[tid + 256];

    float s = v0 + v1;
#pragma unroll
    for (int o = 32; o; o >>= 1) s += __shfl_down(s, o, 64);
    if (lane == 0) red[wv] = s;
    __syncthreads();
    if (tid == 0) bc1 = (red[0] + red[1] + red[2] + red[3]) * (1.0f / DD);
    __syncthreads();
    float mu = bc1;
    float d0 = v0 - mu, d1 = v1 - mu;
    s = d0 * d0 + d1 * d1;
#pragma unroll
    for (int o = 32; o; o >>= 1) s += __shfl_down(s, o, 64);
    if (lane == 0) red[wv] = s;
    __syncthreads();
    if (tid == 0) bc2 = (red[0] + red[1] + red[2] + red[3]) * (1.0f / DD);
    __syncthreads();
    float rstd = rsqrtf(bc2 + 1e-5f);
    xout[(size_t)t * DD + tid]       = f2b(d0 * rstd * g[tid] + b[tid]);
    xout[(size_t)t * DD + tid + 256] = f2b(d1 * rstd * g[tid + 256] + b[tid + 256]);
}

__device__ __forceinline__ float gelu_new(float v) {
    const float c = 0.7978845608028654f;   // sqrt(2/pi)
    float u = c * (v + 0.044715f * v * v * v);
    return 0.5f * v * (1.0f + tanhf(u));
}

// ---------------- all-weight transpose+convert, both layers, one dispatch ----------------
#define PL 3145728   // per-layer bf16 WT region (elements)
__global__ __launch_bounds__(256) void k_wt_all(const float* __restrict__ c_attn_w,
                                                const float* __restrict__ out_w,
                                                const float* __restrict__ c_fc_w,
                                                const float* __restrict__ c_proj_w,
                                                unsigned short* __restrict__ wbuf) {
    __shared__ unsigned short t[64][72];
    int bx = blockIdx.x;
    int l = bx / 768;
    int r = bx - l * 768;
    const float* W; unsigned short* WT; int K, N;
    if (r < 192)      { W = c_attn_w + (size_t)l * 512 * 1536; WT = wbuf + (size_t)l * PL;           K = 512;  N = 1536; }
    else if (r < 256) { r -= 192; W = out_w  + (size_t)l * 512 * 512;  WT = wbuf + (size_t)l * PL + 786432;  K = 512;  N = 512; }
    else if (r < 512) { r -= 256; W = c_fc_w + (size_t)l * 512 * 2048; WT = wbuf + (size_t)l * PL + 1048576; K = 512;  N = 2048; }
    else              { r -= 512; W = c_proj_w + (size_t)l * 2048 * 512; WT = wbuf + (size_t)l * PL + 2097152; K = 2048; N = 512; }
    int tiles_n = N >> 6;
    int n0 = (r % tiles_n) * 64, k0 = (r / tiles_n) * 64;

    int tid = threadIdx.x;
    int rr = tid >> 2;
    int c0 = (tid & 3) * 16;
    const float* src = W + (size_t)(k0 + rr) * N + n0 + c0;
#pragma unroll
    for (int u = 0; u < 4; u++) {
        float4 v = *(const float4*)&src[u * 4];
        t[c0 + u * 4 + 0][rr] = f2b(v.x);
        t[c0 + u * 4 + 1][rr] = f2b(v.y);
        t[c0 + u * 4 + 2][rr] = f2b(v.z);
        t[c0 + u * 4 + 3][rr] = f2b(v.w);
    }
    __syncthreads();
    unsigned short* dst = WT + (size_t)(n0 + rr) * K + k0 + c0;
#pragma unroll
    for (int u = 0; u < 4; u++)
        *(uint2*)&dst[u * 4] = *(const uint2*)&t[rr][c0 + u * 4];
}

// ---------------- MFMA GEMM, double-buffered global_load_lds K-loop ----------------
// C[M x N] = A[M x K](bf16) @ Bt[N x K]^T + bias. 128x128 tile, BK=32, 4 waves, 4x4 frags each.
// One barrier per iter: issue async loads -> buf^1, compute from buf, sync (drains vmcnt).
template <int ACT, int RES, int BF16OUT>
__global__ __launch_bounds__(256) void k_mgemm(const unsigned short* __restrict__ Ab,
                                               const unsigned short* __restrict__ Bt,
                                               const float* __restrict__ bias,
                                               const float* __restrict__ Rp,
                                               float* __restrict__ Cp,
                                               unsigned short* __restrict__ Cb,
                                               int K, int N) {
    __shared__ unsigned short Als[2][8 * 512];   // frag-contiguous: fb mi = 16 rows x 32 k
    __shared__ unsigned short Bls[2][8 * 512];

    int tid = threadIdx.x;
    int l = tid & 63, w = tid >> 6;
    int wm = w >> 1, wn = w & 1;
    int m0 = blockIdx.y * 128, n0 = blockIdx.x * 128;
    int lr = l & 15;
    int lk = (l >> 4) * 8;

    const unsigned short* Ap0 = Ab + (size_t)(m0 + (w * 2 + 0) * 16 + lr) * K + lk;
    const unsigned short* Ap1 = Ab + (size_t)(m0 + (w * 2 + 1) * 16 + lr) * K + lk;
    const unsigned short* Bp0 = Bt + (size_t)(n0 + (w * 2 + 0) * 16 + lr) * K + lk;
    const unsigned short* Bp1 = Bt + (size_t)(n0 + (w * 2 + 1) * 16 + lr) * K + lk;
    int la0 = (w * 2 + 0) * 512 + l * 8;   // LDS element offsets (lane-linear within wave: l*16 B)
    int la1 = (w * 2 + 1) * 512 + l * 8;

    floatx4 acc[4][4];
#pragma unroll
    for (int i = 0; i < 4; i++)
#pragma unroll
        for (int j = 0; j < 4; j++) acc[i][j] = (floatx4){0.f, 0.f, 0.f, 0.f};

    // prologue: stage tile 0 into buf 0
#if HAVE_ASYNC
    g2l16(Ap0, &Als[0][la0]);
    g2l16(Ap1, &Als[0][la1]);
    g2l16(Bp0, &Bls[0][la0]);
    g2l16(Bp1, &Bls[0][la1]);
#else
    *(uint4*)&Als[0][la0] = *(const uint4*)Ap0;
    *(uint4*)&Als[0][la1] = *(const uint4*)Ap1;
    *(uint4*)&Bls[0][la0] = *(const uint4*)Bp0;
    *(uint4*)&Bls[0][la1] = *(const uint4*)Bp1;
#endif

    int nit = K >> 5;
    for (int it = 0; it < nit; it++) {
        int cur = it & 1;
        __syncthreads();   // buf[cur] loads complete (vmcnt drained); buf[cur^1] readers done
        if (it + 1 < nit) {
            int ko = (it + 1) << 5;
#if HAVE_ASYNC
            g2l16(Ap0 + ko, &Als[cur ^ 1][la0]);
            g2l16(Ap1 + ko, &Als[cur ^ 1][la1]);
            g2l16(Bp0 + ko, &Bls[cur ^ 1][la0]);
            g2l16(Bp1 + ko, &Bls[cur ^ 1][la1]);
#else
            *(uint4*)&Als[cur ^ 1][la0] = *(const uint4*)(Ap0 + ko);
            *(uint4*)&Als[cur ^ 1][la1] = *(const uint4*)(Ap1 + ko);
            *(uint4*)&Bls[cur ^ 1][la0] = *(const uint4*)(Bp0 + ko);
            *(uint4*)&Bls[cur ^ 1][la1] = *(const uint4*)(Bp1 + ko);
#endif
        }
        short8 a[4], b[4];
#pragma unroll
        for (int i = 0; i < 4; i++) {
            a[i] = *(const short8*)&Als[cur][(wm * 4 + i) * 512 + l * 8];
            b[i] = *(const short8*)&Bls[cur][(wn * 4 + i) * 512 + l * 8];
        }
#pragma unroll
        for (int i = 0; i < 4; i++)
#pragma unroll
            for (int j = 0; j < 4; j++)
                acc[i][j] = __builtin_amdgcn_mfma_f32_16x16x32_bf16(a[i], b[j], acc[i][j], 0, 0, 0);
    }

    // epilogue: C/D layout col=lane&15, row=(lane>>4)*4+reg
    int col_in = l & 15, rquad = (l >> 4) * 4;
#pragma unroll
    for (int i = 0; i < 4; i++) {
        int gm_base = m0 + wm * 64 + i * 16 + rquad;
#pragma unroll
        for (int j = 0; j < 4; j++) {
            int gn = n0 + wn * 64 + j * 16 + col_in;
            float bv = bias[gn];
#pragma unroll
            for (int r = 0; r < 4; r++) {
                size_t off = (size_t)(gm_base + r) * N + gn;
                float v = acc[i][j][r] + bv;
                if (ACT) v = gelu_new(v);
                if (RES) v += Rp[off];
                if (BF16OUT) Cb[off] = f2b(v);
                else Cp[off] = v;
            }
        }
    }
}

// ---------------- MFMA flash attention, S computed transposed ----------------
// qkv bf16 [T,1536] (q|k|v). Max-free softmax: p = exp(s/8 - 8), exact p=0 on diagonal.
// S^T = K·Q^T (A=K, B=Q): C/D gives lane 4 consecutive keys at fixed query m=lr ->
// P written to Pls[m][key] with 4x ds_write_b64; single scalar lsum per lane.
__global__ __launch_bounds__(256) void k_attn_mfma(const unsigned short* __restrict__ qkv,
                                                   unsigned short* __restrict__ xatt) {
    __shared__ unsigned short Ks[64 * 72];    // K tile [key][d]
    __shared__ unsigned short Vt[64 * 72];    // V^T tile [d][key]
    __shared__ unsigned short Pls[64 * 72];   // P tile [m][key]

    int qt = blockIdx.x, hd = blockIdx.y, b = blockIdx.z;
    int tid = threadIdx.x;
    int l = tid & 63, w = tid >> 6;
    int lr = l & 15, quad = l >> 4;

    const size_t base = (size_t)b * NN * 1536;

    // Q frags (B-operand): lane col m=lr, k=d=quad*8+j (+32*ss) — same bytes as A-layout
    short8 qf[2];
    {
        const unsigned short* qrow = qkv + base + (size_t)(qt * 64 + w * 16 + lr) * 1536 + hd * 64;
        qf[0] = *(const short8*)&qrow[quad * 8];
        qf[1] = *(const short8*)&qrow[quad * 8 + 32];
    }

    floatx4 O[4];   // O[m=quad*4+reg][d=jd*16+lr]
#pragma unroll
    for (int jd = 0; jd < 4; jd++) O[jd] = (floatx4){0.f, 0.f, 0.f, 0.f};
    float lsum = 0.0f;   // per-lane partial row-sum for query m = w*16+lr

    // staging maps
    int sr = tid >> 2, sc = (tid & 3) * 16;          // K: row sr (key), 16-d chunk sc
    int vk = (tid & 15) * 4, vd = (tid >> 4) * 4;    // V: 4 keys x 4 d per thread
    const unsigned short* Kbase = qkv + base + 512 + hd * 64;
    const unsigned short* Vbase = qkv + base + 1024 + hd * 64;

    uint4 rk0, rk1;
    union { uint2 u; unsigned short s[4]; } rv[4];
    rk0 = *(const uint4*)&Kbase[(size_t)sr * 1536 + sc];
    rk1 = *(const uint4*)&Kbase[(size_t)sr * 1536 + sc + 8];
#pragma unroll
    for (int i = 0; i < 4; i++)
        rv[i].u = *(const uint2*)&Vbase[(size_t)(vk + i) * 1536 + vd];

    for (int kt = 0; kt < 32; kt++) {
        __syncthreads();   // prev iter's Ks/Vt reads done
        *(uint4*)&Ks[sr * 72 + sc]     = rk0;
        *(uint4*)&Ks[sr * 72 + sc + 8] = rk1;
#pragma unroll
        for (int j = 0; j < 4; j++) {
            union { uint2 u; unsigned short s[4]; } pk;
            pk.s[0] = rv[0].s[j]; pk.s[1] = rv[1].s[j];
            pk.s[2] = rv[2].s[j]; pk.s[3] = rv[3].s[j];
            *(uint2*)&Vt[(vd + j) * 72 + vk] = pk.u;
        }
        __syncthreads();
        if (kt < 31) {   // prefetch next K/V tile
            int kn = (kt + 1) * 64;
            rk0 = *(const uint4*)&Kbase[(size_t)(kn + sr) * 1536 + sc];
            rk1 = *(const uint4*)&Kbase[(size_t)(kn + sr) * 1536 + sc + 8];
#pragma unroll
            for (int i = 0; i < 4; i++)
                rv[i].u = *(const uint2*)&Vbase[(size_t)(kn + vk + i) * 1536 + vd];
        }

        // S^T = K Q^T: s[jn] rows key=jn*16+quad*4+reg, col m=lr
        floatx4 s[4];
#pragma unroll
        for (int jn = 0; jn < 4; jn++) s[jn] = (floatx4){0.f, 0.f, 0.f, 0.f};
#pragma unroll
        for (int ss = 0; ss < 2; ss++)
#pragma unroll
            for (int jn = 0; jn < 4; jn++) {
                short8 ak = *(const short8*)&Ks[(jn * 16 + lr) * 72 + ss * 32 + quad * 8];
                s[jn] = __builtin_amdgcn_mfma_f32_16x16x32_bf16(ak, qf[ss], s[jn], 0, 0, 0);
            }

        // p = exp(s/8 - 8); mask diag; accumulate lsum; pack 4 consecutive keys -> b64 write
        int mq = w * 16 + lr;   // query index within 64-row q tile
#pragma unroll
        for (int jn = 0; jn < 4; jn++) {
            union { uint2 u; unsigned short h[4]; } pk;
#pragma unroll
            for (int r = 0; r < 4; r++) {
                float p = __expf(s[jn][r] * 0.125f - 8.0f);
                if (kt == qt && mq == jn * 16 + quad * 4 + r) p = 0.0f;
                lsum += p;
                pk.h[r] = f2b(p);
            }
            *(uint2*)&Pls[mq * 72 + jn * 16 + quad * 4] = pk.u;
        }

        // O += P V   (P rows written/read by the same wave; no barrier needed)
#pragma unroll
        for (int ss = 0; ss < 2; ss++) {
            short8 ap = *(const short8*)&Pls[(w * 16 + lr) * 72 + ss * 32 + quad * 8];
#pragma unroll
            for (int jd = 0; jd < 4; jd++) {
                short8 bv = *(const short8*)&Vt[(jd * 16 + lr) * 72 + ss * 32 + quad * 8];
                O[jd] = __builtin_amdgcn_mfma_f32_16x16x32_bf16(ap, bv, O[jd], 0, 0, 0);
            }
        }
    }

    // reduce lsum across quads (lanes lr, lr+16, lr+32, lr+48 hold same query)
    lsum += __shfl_xor(lsum, 16);
    lsum += __shfl_xor(lsum, 32);
    // normalize + store: O rows are m=quad*4+r; fetch that query's total from lane quad*4+r (width 16)
#pragma unroll
    for (int r = 0; r < 4; r++) {
        float inv = 1.0f / __shfl(lsum, quad * 4 + r, 16);
        size_t tok = (size_t)b * NN + qt * 64 + w * 16 + quad * 4 + r;
#pragma unroll
        for (int jd = 0; jd < 4; jd++)
            xatt[tok * DD + hd * 64 + jd * 16 + lr] = f2b(O[jd][r] * inv);
    }
}

extern "C" void kernel_launch(void* const* d_in, const int* in_sizes, int n_in,
                              void* d_out, int out_size, void* d_ws, size_t ws_size,
                              hipStream_t stream) {
    const float* emb      = (const float*)d_in[0];
    const float* pos      = (const float*)d_in[1];
    const float* c_attn_w = (const float*)d_in[2];
    const float* c_attn_b = (const float*)d_in[3];
    const float* out_w    = (const float*)d_in[4];
    const float* out_b    = (const float*)d_in[5];
    const float* ln1_g    = (const float*)d_in[6];
    const float* ln1_b    = (const float*)d_in[7];
    const float* c_fc_w   = (const float*)d_in[8];
    const float* c_fc_b   = (const float*)d_in[9];
    const float* c_proj_w = (const float*)d_in[10];
    const float* c_proj_b = (const float*)d_in[11];
    const float* ln2_g    = (const float*)d_in[12];
    const float* ln2_b    = (const float*)d_in[13];

    // workspace: 8 + 16.8 + 4 + 4 + 12.6 = ~45.4 MB
    char* p = (char*)d_ws;
    float* h = (float*)p;                       p += (size_t)TT * DD * 4;      // fp32 residual
    unsigned short* act = (unsigned short*)p;   p += (size_t)TT * 2048 * 2;    // qkvb [T,1536] / ffa [T,2048] union
    unsigned short* x = (unsigned short*)p;     p += (size_t)TT * DD * 2;      // LN out
    unsigned short* xatt = (unsigned short*)p;  p += (size_t)TT * DD * 2;      // attn out
    unsigned short* wbuf = (unsigned short*)p;                                 // both layers' bf16 W^T

    unsigned short* qkvb = act;
    unsigned short* ffa  = act;
    float* out = (float*)d_out;

    k_embed<<<TT * DD / 256, 256, 0, stream>>>(emb, pos, h);
    k_wt_all<<<1536, 256, 0, stream>>>(c_attn_w, out_w, c_fc_w, c_proj_w, wbuf);

    for (int l = 0; l < LL; l++) {
        unsigned short* wqkv_t  = wbuf + (size_t)l * PL;
        unsigned short* wout_t  = wqkv_t + 786432;
        unsigned short* wfc_t   = wqkv_t + 1048576;
        unsigned short* wproj_t = wqkv_t + 2097152;
        float* proj_dst = (l == LL - 1) ? out : h;   // last proj writes d_out directly

        // x = LN1(h)
        k_ln<<<TT, 256, 0, stream>>>(h, x, ln1_g + l * DD, ln1_b + l * DD);
        // qkvb = x @ Wqkv + b  (bf16)
        k_mgemm<0, 0, 1><<<dim3(1536 / 128, TT / 128), 256, 0, stream>>>(
            x, wqkv_t, c_attn_b + l * 1536, nullptr, nullptr, qkvb, 512, 1536);
        // xatt = attention(qkvb)  (bf16)
        k_attn_mfma<<<dim3(NN / 64, HH, BB), 256, 0, stream>>>(qkvb, xatt);
        // h = xatt @ Wout + b + h  (fp32)
        k_mgemm<0, 1, 0><<<dim3(512 / 128, TT / 128), 256, 0, stream>>>(
            xatt, wout_t, out_b + l * 512, h, h, nullptr, 512, 512);
        // x = LN2(h)
        k_ln<<<TT, 256, 0, stream>>>(h, x, ln2_g + l * DD, ln2_b + l * DD);
        // ffa = gelu(x @ Wfc + b)  (bf16; qkvb dead)
        k_mgemm<1, 0, 1><<<dim3(2048 / 128, TT / 128), 256, 0, stream>>>(
            x, wfc_t, c_fc_b + l * 2048, nullptr, nullptr, ffa, 512, 2048);
        // h/out = ffa @ Wproj + b + h  (fp32)
        k_mgemm<0, 1, 0><<<dim3(512 / 128, TT / 128), 256, 0, stream>>>(
            ffa, wproj_t, c_proj_b + l * 512, h, proj_dst, nullptr, 2048, 512);
    }
}

// Round 7
// 450.301 us; speedup vs baseline: 1.0264x; 1.0264x over previous
//
#include <hip/hip_runtime.h>
#include <hip/hip_bf16.h>
#include <math.h>

#define BB 2
#define NN 2048
#define DD 512
#define HH 8
#define LL 2
#define TT (BB*NN)   // 4096 tokens

typedef short short8 __attribute__((ext_vector_type(8)));
typedef float floatx4 __attribute__((ext_vector_type(4)));

__device__ __forceinline__ unsigned short f2b(float v) {
    union { float f; unsigned u; } x; x.f = v;
    unsigned r = x.u + 0x7fff + ((x.u >> 16) & 1);   // RNE
    return (unsigned short)(r >> 16);
}

// ---------------- embed: h = inputs_embeds + pos_emb ----------------
__global__ __launch_bounds__(256) void k_embed(const float* __restrict__ emb,
                                               const float* __restrict__ pos,
                                               float* __restrict__ h) {
    int i = blockIdx.x * 256 + threadIdx.x;
    h[i] = emb[i] + pos[i & (NN * DD - 1)];
}

// ---------------- dst = src + bias (row-broadcast); src may alias dst ----------------
__global__ __launch_bounds__(256) void k_bias_add(const float* __restrict__ src,
                                                  const float* __restrict__ bias,
                                                  float* __restrict__ dst) {
    int i = blockIdx.x * 256 + threadIdx.x;
    dst[i] = src[i] + bias[i & (DD - 1)];
}

// ---------------- layernorm: x = LN(h)*g + b  (bf16 out), one block per token ----------------
__global__ __launch_bounds__(256) void k_ln(const float* __restrict__ hin,
                                            unsigned short* __restrict__ xout,
                                            const float* __restrict__ g,
                                            const float* __restrict__ b) {
    __shared__ float red[4];
    __shared__ float bc1, bc2;
    int t = blockIdx.x;
    int tid = threadIdx.x;
    int lane = tid & 63, wv = tid >> 6;
    const float* row = hin + (size_t)t * DD;
    float v0 = row[tid];
    float v1 = row[tid + 256];

    float s = v0 + v1;
#pragma unroll
    for (int o = 32; o; o >>= 1) s += __shfl_down(s, o, 64);
    if (lane == 0) red[wv] = s;
    __syncthreads();
    if (tid == 0) bc1 = (red[0] + red[1] + red[2] + red[3]) * (1.0f / DD);
    __syncthreads();
    float mu = bc1;
    float d0 = v0 - mu, d1 = v1 - mu;
    s = d0 * d0 + d1 * d1;
#pragma unroll
    for (int o = 32; o; o >>= 1) s += __shfl_down(s, o, 64);
    if (lane == 0) red[wv] = s;
    __syncthreads();
    if (tid == 0) bc2 = (red[0] + red[1] + red[2] + red[3]) * (1.0f / DD);
    __syncthreads();
    float rstd = rsqrtf(bc2 + 1e-5f);
    xout[(size_t)t * DD + tid]       = f2b(d0 * rstd * g[tid] + b[tid]);
    xout[(size_t)t * DD + tid + 256] = f2b(d1 * rstd * g[tid + 256] + b[tid + 256]);
}

__device__ __forceinline__ float gelu_new(float v) {
    const float c = 0.7978845608028654f;   // sqrt(2/pi)
    float u = c * (v + 0.044715f * v * v * v);
    return 0.5f * v * (1.0f + tanhf(u));
}

// ---------------- all-weight transpose+convert, both layers, one dispatch ----------------
#define PL 3145728   // per-layer bf16 WT region (elements)
__global__ __launch_bounds__(256) void k_wt_all(const float* __restrict__ c_attn_w,
                                                const float* __restrict__ out_w,
                                                const float* __restrict__ c_fc_w,
                                                const float* __restrict__ c_proj_w,
                                                unsigned short* __restrict__ wbuf) {
    __shared__ unsigned short t[64][72];
    int bx = blockIdx.x;
    int l = bx / 768;
    int r = bx - l * 768;
    const float* W; unsigned short* WT; int K, N;
    if (r < 192)      { W = c_attn_w + (size_t)l * 512 * 1536; WT = wbuf + (size_t)l * PL;           K = 512;  N = 1536; }
    else if (r < 256) { r -= 192; W = out_w  + (size_t)l * 512 * 512;  WT = wbuf + (size_t)l * PL + 786432;  K = 512;  N = 512; }
    else if (r < 512) { r -= 256; W = c_fc_w + (size_t)l * 512 * 2048; WT = wbuf + (size_t)l * PL + 1048576; K = 512;  N = 2048; }
    else              { r -= 512; W = c_proj_w + (size_t)l * 2048 * 512; WT = wbuf + (size_t)l * PL + 2097152; K = 2048; N = 512; }
    int tiles_n = N >> 6;
    int n0 = (r % tiles_n) * 64, k0 = (r / tiles_n) * 64;

    int tid = threadIdx.x;
    int rr = tid >> 2;
    int c0 = (tid & 3) * 16;
    const float* src = W + (size_t)(k0 + rr) * N + n0 + c0;
#pragma unroll
    for (int u = 0; u < 4; u++) {
        float4 v = *(const float4*)&src[u * 4];
        t[c0 + u * 4 + 0][rr] = f2b(v.x);
        t[c0 + u * 4 + 1][rr] = f2b(v.y);
        t[c0 + u * 4 + 2][rr] = f2b(v.z);
        t[c0 + u * 4 + 3][rr] = f2b(v.w);
    }
    __syncthreads();
    unsigned short* dst = WT + (size_t)(n0 + rr) * K + k0 + c0;
#pragma unroll
    for (int u = 0; u < 4; u++)
        *(uint2*)&dst[u * 4] = *(const uint2*)&t[rr][c0 + u * 4];
}

// ---------------- MFMA GEMM (round-5 reg-prefetch K-loop) + optional split-K atomics ------
// C[M x N] (+)= A[M x K](bf16) @ Bt[N x K]^T. 128x128 tile, BK=32, 4 waves, 4x4 frags each.
// Row stride = Kfull; this block covers K-chunk [blockIdx.z*Kchunk, +Kchunk).
// ATOMIC: epilogue atomicAdd(Cp) with no bias/act/res (dst pre-initialized with bias+residual).
template <int ACT, int RES, int BF16OUT, int ATOMIC>
__global__ __launch_bounds__(256) void k_mgemm(const unsigned short* __restrict__ Ab,
                                               const unsigned short* __restrict__ Bt,
                                               const float* __restrict__ bias,
                                               const float* __restrict__ Rp,
                                               float* __restrict__ Cp,
                                               unsigned short* __restrict__ Cb,
                                               int Kfull, int Kchunk, int N) {
    __shared__ unsigned short Als[8 * 512];   // 8 frag-blocks (16 rows x 32 k), fragment-contiguous
    __shared__ unsigned short Bls[8 * 512];

    int tid = threadIdx.x;
    int l = tid & 63, w = tid >> 6;
    int wm = w >> 1, wn = w & 1;
    int m0 = blockIdx.y * 128, n0 = blockIdx.x * 128;
    int kb = blockIdx.z * Kchunk;
    int lr = l & 15;
    int lk = (l >> 4) * 8;

    const unsigned short* Ap0 = Ab + (size_t)(m0 + (w * 2 + 0) * 16 + lr) * Kfull + kb + lk;
    const unsigned short* Ap1 = Ab + (size_t)(m0 + (w * 2 + 1) * 16 + lr) * Kfull + kb + lk;
    const unsigned short* Bp0 = Bt + (size_t)(n0 + (w * 2 + 0) * 16 + lr) * Kfull + kb + lk;
    const unsigned short* Bp1 = Bt + (size_t)(n0 + (w * 2 + 1) * 16 + lr) * Kfull + kb + lk;

    floatx4 acc[4][4];
#pragma unroll
    for (int i = 0; i < 4; i++)
#pragma unroll
        for (int j = 0; j < 4; j++) acc[i][j] = (floatx4){0.f, 0.f, 0.f, 0.f};

    // prefetch tile 0
    uint4 ra0 = *(const uint4*)Ap0;
    uint4 ra1 = *(const uint4*)Ap1;
    uint4 rb0 = *(const uint4*)Bp0;
    uint4 rb1 = *(const uint4*)Bp1;

    for (int k0 = 0; k0 < Kchunk; k0 += 32) {
        __syncthreads();   // prev iter's frag reads done; LDS reusable
        *(uint4*)&Als[(w * 2 + 0) * 512 + l * 8] = ra0;
        *(uint4*)&Als[(w * 2 + 1) * 512 + l * 8] = ra1;
        *(uint4*)&Bls[(w * 2 + 0) * 512 + l * 8] = rb0;
        *(uint4*)&Bls[(w * 2 + 1) * 512 + l * 8] = rb1;
        __syncthreads();
        if (k0 + 32 < Kchunk) {   // prefetch next tile; waited at next iter's LDS store
            ra0 = *(const uint4*)(Ap0 + k0 + 32);
            ra1 = *(const uint4*)(Ap1 + k0 + 32);
            rb0 = *(const uint4*)(Bp0 + k0 + 32);
            rb1 = *(const uint4*)(Bp1 + k0 + 32);
        }
        short8 a[4], b[4];
#pragma unroll
        for (int i = 0; i < 4; i++) {
            a[i] = *(const short8*)&Als[(wm * 4 + i) * 512 + l * 8];
            b[i] = *(const short8*)&Bls[(wn * 4 + i) * 512 + l * 8];
        }
#pragma unroll
        for (int i = 0; i < 4; i++)
#pragma unroll
            for (int j = 0; j < 4; j++)
                acc[i][j] = __builtin_amdgcn_mfma_f32_16x16x32_bf16(a[i], b[j], acc[i][j], 0, 0, 0);
    }

    // epilogue: C/D layout col=lane&15, row=(lane>>4)*4+reg
    int col_in = l & 15, rquad = (l >> 4) * 4;
#pragma unroll
    for (int i = 0; i < 4; i++) {
        int gm_base = m0 + wm * 64 + i * 16 + rquad;
#pragma unroll
        for (int j = 0; j < 4; j++) {
            int gn = n0 + wn * 64 + j * 16 + col_in;
            float bv = ATOMIC ? 0.0f : bias[gn];
#pragma unroll
            for (int r = 0; r < 4; r++) {
                size_t off = (size_t)(gm_base + r) * N + gn;
                if (ATOMIC) {
                    atomicAdd(&Cp[off], acc[i][j][r]);
                } else {
                    float v = acc[i][j][r] + bv;
                    if (ACT) v = gelu_new(v);
                    if (RES) v += Rp[off];
                    if (BF16OUT) Cb[off] = f2b(v);
                    else Cp[off] = v;
                }
            }
        }
    }
}

// ---------------- MFMA flash attention, S computed transposed ----------------
// qkv bf16 [T,1536] (q|k|v). Max-free softmax: p = exp(s/8 - 8), exact p=0 on diagonal.
// S^T = K·Q^T (A=K, B=Q): C/D gives lane 4 consecutive keys at fixed query m=lr ->
// P written to Pls[m][key] with 4x ds_write_b64; single scalar lsum per lane.
__global__ __launch_bounds__(256) void k_attn_mfma(const unsigned short* __restrict__ qkv,
                                                   unsigned short* __restrict__ xatt) {
    __shared__ unsigned short Ks[64 * 72];    // K tile [key][d]
    __shared__ unsigned short Vt[64 * 72];    // V^T tile [d][key]
    __shared__ unsigned short Pls[64 * 72];   // P tile [m][key]

    int qt = blockIdx.x, hd = blockIdx.y, b = blockIdx.z;
    int tid = threadIdx.x;
    int l = tid & 63, w = tid >> 6;
    int lr = l & 15, quad = l >> 4;

    const size_t base = (size_t)b * NN * 1536;

    // Q frags (B-operand): lane col m=lr, k=d=quad*8+j (+32*ss)
    short8 qf[2];
    {
        const unsigned short* qrow = qkv + base + (size_t)(qt * 64 + w * 16 + lr) * 1536 + hd * 64;
        qf[0] = *(const short8*)&qrow[quad * 8];
        qf[1] = *(const short8*)&qrow[quad * 8 + 32];
    }

    floatx4 O[4];   // O[m=quad*4+reg][d=jd*16+lr]
#pragma unroll
    for (int jd = 0; jd < 4; jd++) O[jd] = (floatx4){0.f, 0.f, 0.f, 0.f};
    float lsum = 0.0f;   // per-lane partial row-sum for query m = w*16+lr

    // staging maps
    int sr = tid >> 2, sc = (tid & 3) * 16;          // K: row sr (key), 16-d chunk sc
    int vk = (tid & 15) * 4, vd = (tid >> 4) * 4;    // V: 4 keys x 4 d per thread
    const unsigned short* Kbase = qkv + base + 512 + hd * 64;
    const unsigned short* Vbase = qkv + base + 1024 + hd * 64;

    uint4 rk0, rk1;
    union { uint2 u; unsigned short s[4]; } rv[4];
    rk0 = *(const uint4*)&Kbase[(size_t)sr * 1536 + sc];
    rk1 = *(const uint4*)&Kbase[(size_t)sr * 1536 + sc + 8];
#pragma unroll
    for (int i = 0; i < 4; i++)
        rv[i].u = *(const uint2*)&Vbase[(size_t)(vk + i) * 1536 + vd];

    for (int kt = 0; kt < 32; kt++) {
        __syncthreads();   // prev iter's Ks/Vt reads done
        *(uint4*)&Ks[sr * 72 + sc]     = rk0;
        *(uint4*)&Ks[sr * 72 + sc + 8] = rk1;
#pragma unroll
        for (int j = 0; j < 4; j++) {
            union { uint2 u; unsigned short s[4]; } pk;
            pk.s[0] = rv[0].s[j]; pk.s[1] = rv[1].s[j];
            pk.s[2] = rv[2].s[j]; pk.s[3] = rv[3].s[j];
            *(uint2*)&Vt[(vd + j) * 72 + vk] = pk.u;
        }
        __syncthreads();
        if (kt < 31) {   // prefetch next K/V tile
            int kn = (kt + 1) * 64;
            rk0 = *(const uint4*)&Kbase[(size_t)(kn + sr) * 1536 + sc];
            rk1 = *(const uint4*)&Kbase[(size_t)(kn + sr) * 1536 + sc + 8];
#pragma unroll
            for (int i = 0; i < 4; i++)
                rv[i].u = *(const uint2*)&Vbase[(size_t)(kn + vk + i) * 1536 + vd];
        }

        // S^T = K Q^T: s[jn] rows key=jn*16+quad*4+reg, col m=lr
        floatx4 s[4];
#pragma unroll
        for (int jn = 0; jn < 4; jn++) s[jn] = (floatx4){0.f, 0.f, 0.f, 0.f};
#pragma unroll
        for (int ss = 0; ss < 2; ss++)
#pragma unroll
            for (int jn = 0; jn < 4; jn++) {
                short8 ak = *(const short8*)&Ks[(jn * 16 + lr) * 72 + ss * 32 + quad * 8];
                s[jn] = __builtin_amdgcn_mfma_f32_16x16x32_bf16(ak, qf[ss], s[jn], 0, 0, 0);
            }

        // p = exp(s/8 - 8); mask diag; accumulate lsum; pack 4 consecutive keys -> b64 write
        int mq = w * 16 + lr;   // query index within 64-row q tile
#pragma unroll
        for (int jn = 0; jn < 4; jn++) {
            union { uint2 u; unsigned short h[4]; } pk;
#pragma unroll
            for (int r = 0; r < 4; r++) {
                float p = __expf(s[jn][r] * 0.125f - 8.0f);
                if (kt == qt && mq == jn * 16 + quad * 4 + r) p = 0.0f;
                lsum += p;
                pk.h[r] = f2b(p);
            }
            *(uint2*)&Pls[mq * 72 + jn * 16 + quad * 4] = pk.u;
        }

        // O += P V   (P rows written/read by the same wave; no barrier needed)
#pragma unroll
        for (int ss = 0; ss < 2; ss++) {
            short8 ap = *(const short8*)&Pls[(w * 16 + lr) * 72 + ss * 32 + quad * 8];
#pragma unroll
            for (int jd = 0; jd < 4; jd++) {
                short8 bv = *(const short8*)&Vt[(jd * 16 + lr) * 72 + ss * 32 + quad * 8];
                O[jd] = __builtin_amdgcn_mfma_f32_16x16x32_bf16(ap, bv, O[jd], 0, 0, 0);
            }
        }
    }

    // reduce lsum across quads (lanes lr, lr+16, lr+32, lr+48 hold same query)
    lsum += __shfl_xor(lsum, 16);
    lsum += __shfl_xor(lsum, 32);
#pragma unroll
    for (int r = 0; r < 4; r++) {
        float inv = 1.0f / __shfl(lsum, quad * 4 + r, 16);
        size_t tok = (size_t)b * NN + qt * 64 + w * 16 + quad * 4 + r;
#pragma unroll
        for (int jd = 0; jd < 4; jd++)
            xatt[tok * DD + hd * 64 + jd * 16 + lr] = f2b(O[jd][r] * inv);
    }
}

extern "C" void kernel_launch(void* const* d_in, const int* in_sizes, int n_in,
                              void* d_out, int out_size, void* d_ws, size_t ws_size,
                              hipStream_t stream) {
    const float* emb      = (const float*)d_in[0];
    const float* pos      = (const float*)d_in[1];
    const float* c_attn_w = (const float*)d_in[2];
    const float* c_attn_b = (const float*)d_in[3];
    const float* out_w    = (const float*)d_in[4];
    const float* out_b    = (const float*)d_in[5];
    const float* ln1_g    = (const float*)d_in[6];
    const float* ln1_b    = (const float*)d_in[7];
    const float* c_fc_w   = (const float*)d_in[8];
    const float* c_fc_b   = (const float*)d_in[9];
    const float* c_proj_w = (const float*)d_in[10];
    const float* c_proj_b = (const float*)d_in[11];
    const float* ln2_g    = (const float*)d_in[12];
    const float* ln2_b    = (const float*)d_in[13];

    // workspace: 8 + 16.8 + 4 + 4 + 12.6 = ~45.4 MB
    char* p = (char*)d_ws;
    float* h = (float*)p;                       p += (size_t)TT * DD * 4;      // fp32 residual
    unsigned short* act = (unsigned short*)p;   p += (size_t)TT * 2048 * 2;    // qkvb [T,1536] / ffa [T,2048] union
    unsigned short* x = (unsigned short*)p;     p += (size_t)TT * DD * 2;      // LN out
    unsigned short* xatt = (unsigned short*)p;  p += (size_t)TT * DD * 2;      // attn out
    unsigned short* wbuf = (unsigned short*)p;                                 // both layers' bf16 W^T

    unsigned short* qkvb = act;
    unsigned short* ffa  = act;
    float* out = (float*)d_out;

    k_embed<<<TT * DD / 256, 256, 0, stream>>>(emb, pos, h);
    k_wt_all<<<1536, 256, 0, stream>>>(c_attn_w, out_w, c_fc_w, c_proj_w, wbuf);

    for (int l = 0; l < LL; l++) {
        unsigned short* wqkv_t  = wbuf + (size_t)l * PL;
        unsigned short* wout_t  = wqkv_t + 786432;
        unsigned short* wfc_t   = wqkv_t + 1048576;
        unsigned short* wproj_t = wqkv_t + 2097152;
        float* proj_dst = (l == LL - 1) ? out : h;   // last proj accumulates into d_out

        // x = LN1(h)
        k_ln<<<TT, 256, 0, stream>>>(h, x, ln1_g + l * DD, ln1_b + l * DD);
        // qkvb = x @ Wqkv + b  (bf16)
        k_mgemm<0, 0, 1, 0><<<dim3(1536 / 128, TT / 128), 256, 0, stream>>>(
            x, wqkv_t, c_attn_b + l * 1536, nullptr, nullptr, qkvb, 512, 512, 1536);
        // xatt = attention(qkvb)  (bf16)
        k_attn_mfma<<<dim3(NN / 64, HH, BB), 256, 0, stream>>>(qkvb, xatt);
        // h = h + out_b ; h += xatt @ Wout  (split-K=2 atomics)
        k_bias_add<<<TT * DD / 256, 256, 0, stream>>>(h, out_b + l * DD, h);
        k_mgemm<0, 0, 0, 1><<<dim3(512 / 128, TT / 128, 2), 256, 0, stream>>>(
            xatt, wout_t, nullptr, nullptr, h, nullptr, 512, 256, 512);
        // x = LN2(h)
        k_ln<<<TT, 256, 0, stream>>>(h, x, ln2_g + l * DD, ln2_b + l * DD);
        // ffa = gelu(x @ Wfc + b)  (bf16; qkvb dead)
        k_mgemm<1, 0, 1, 0><<<dim3(2048 / 128, TT / 128), 256, 0, stream>>>(
            x, wfc_t, c_fc_b + l * 2048, nullptr, nullptr, ffa, 512, 512, 2048);
        // proj_dst = h + proj_b ; proj_dst += ffa @ Wproj  (split-K=4 atomics)
        k_bias_add<<<TT * DD / 256, 256, 0, stream>>>(h, c_proj_b + l * DD, proj_dst);
        k_mgemm<0, 0, 0, 1><<<dim3(512 / 128, TT / 128, 4), 256, 0, stream>>>(
            ffa, wproj_t, nullptr, nullptr, proj_dst, nullptr, 2048, 512, 512);
    }
}